// Round 8
// baseline (436.412 us; speedup 1.0000x reference)
//
#include <hip/hip_runtime.h>
#include <math.h>

// Problem constants: B=2, T=2048, H=8, Dk=64, D=512
#define BB 2
#define TT 2048
#define HH 8
#define DK 64
#define DD 512
#define MM (BB * TT)

typedef unsigned int u32;
typedef unsigned short u16;
typedef __bf16 bf16x8 __attribute__((ext_vector_type(8)));
typedef float f32x4 __attribute__((ext_vector_type(4)));

union frag_u { bf16x8 f; u16 u[8]; u32 w[4]; };

// fp32 -> bf16 hi + bf16 lo (RNE both); x ~= hi + lo to ~2^-20 rel.
__device__ __forceinline__ void split2(float x, u16& h, u16& l) {
    u32 u = __float_as_uint(x);
    u32 hi = (u + 0x7fffu + ((u >> 16) & 1u)) >> 16;
    float hif = __uint_as_float(hi << 16);
    float lof = x - hif;                       // exact
    u32 ul = __float_as_uint(lof);
    u32 lo = (ul + 0x7fffu + ((ul >> 16) & 1u)) >> 16;
    h = (u16)hi; l = (u16)lo;
}
__device__ __forceinline__ u32 split_pack(float x) {
    u16 h, l; split2(x, h, l);
    return ((u32)h << 16) | (u32)l;
}

// async global->LDS, 16B per lane, LDS dest = wave-uniform base + lane*16
__device__ __forceinline__ void load_lds16(const void* g, void* l) {
    __builtin_amdgcn_global_load_lds(
        (const __attribute__((address_space(1))) void*)g,
        (__attribute__((address_space(3))) void*)l, 16, 0, 0);
}

// ---------------------------------------------------------------------------
// Sinusoid position encoding (fp64 math to match numpy float64 path).
// ---------------------------------------------------------------------------
__global__ __launch_bounds__(256) void pe_kernel(float* __restrict__ pe) {
    int idx = blockIdx.x * 256 + threadIdx.x;
    int m   = idx >> 9;
    int col = idx & 511;
    int j   = col & 255;
    double inv_freq = exp((double)(-2 * j) * (9.210340371976184 / 512.0));
    double ang = (double)(TT - m) * inv_freq;
    pe[idx] = (col < 256) ? (float)sin(ang) : (float)cos(ang);
}

// ---------------------------------------------------------------------------
// Bias-fold dots, PRESCALED by 1/8, stored HEAD-MAJOR:
//   cbk[(h*B + b)*T + t]  = 0.125 * content_bias[h] . k[b,t,h,:]
//   rbrk[h*2T + m]        = 0.125 * relative_bias[h] . relk[m,h,:]
// ---------------------------------------------------------------------------
__global__ __launch_bounds__(256) void bias_dots_kernel(
    const float* __restrict__ kmat, const float* __restrict__ relk,
    const float* __restrict__ cb, const float* __restrict__ rb,
    float* __restrict__ cbk, float* __restrict__ rbrk) {
    int idx = blockIdx.x * 256 + threadIdx.x;
    if (idx < BB * TT * HH) {
        int h = idx & (HH - 1);
        int bt = idx >> 3;                 // b*T + t
        int b = bt >> 11, t = bt & (TT - 1);
        const float* kp  = kmat + (size_t)idx * DK;
        const float* cbp = cb + h * DK;
        float s = 0.f;
#pragma unroll
        for (int d = 0; d < DK; d++) s += cbp[d] * kp[d];
        cbk[((size_t)h * BB + b) * TT + t] = s * 0.125f;
    } else {
        int i2 = idx - BB * TT * HH;       // m*H + h
        int h = i2 & (HH - 1);
        int m = i2 >> 3;
        const float* rp  = relk + (size_t)i2 * DK;
        const float* rbp = rb + h * DK;
        float s = 0.f;
#pragma unroll
        for (int d = 0; d < DK; d++) s += rbp[d] * rp[d];
        rbrk[(size_t)h * (2 * TT) + m] = s * 0.125f;
    }
}

// ---------------------------------------------------------------------------
// Prepack fp32 32x64 tiles into hi/lo bf16 layouts (8 KB/tile, hi [0,4KB),
// lo [4,8KB)).
//   mode 0: K tiles (bid: b=bid>>9, h=(bid>>6)&7, jt=bid&63) — LDS-swizzled
//     B-frag granules: g = nt*128 + n*8 + ((4s+kq+5n)&7) (read via LDS).
//   mode 1: R chunks (bid: h=bid>>7, cidx=bid&127) — LANE-ORDER coalesced:
//     region (nt*2+s) of 512 u16; granule at region*512 + lane*8 holds
//     R[n=nt*16+c][k=s*32+quad*8+e] — frag = one coalesced 1KB global load.
//   mode 2: V tiles (K-style bid) — LANE-ORDER coalesced, transposed:
//     region ntd; granule at ntd*512 + lane*8 holds V[j=quad*8+e][d=ntd*16+c].
// ---------------------------------------------------------------------------
__global__ __launch_bounds__(256) void prepack_kernel(
    const float* __restrict__ src, u16* __restrict__ dst, int mode) {
    __shared__ float tf[32][68];
    const int bid = blockIdx.x, tid = threadIdx.x;
    size_t soff;
    if (mode == 1) soff = ((size_t)(bid & 127) * 256 + (size_t)(bid >> 7)) * 64;
    else soff = ((size_t)(bid >> 9) * 2048 + (size_t)(bid & 63) * 32) * 512
                + (size_t)((bid >> 6) & 7) * 64;
    u16* dt = dst + (size_t)bid * 4096;
    if (mode == 1) {
        // lane-order B-frag layout, no LDS needed
        const int region = tid >> 6, lane = tid & 63;
        const int q2 = lane >> 4, c2 = lane & 15;
        const int nt = region >> 1, s = region & 1;
        const float* p = src + soff + (size_t)(nt * 16 + c2) * 512
                             + s * 32 + q2 * 8;
        float4 a  = *(const float4*)p;
        float4 b4 = *(const float4*)(p + 4);
        float xs[8] = {a.x, a.y, a.z, a.w, b4.x, b4.y, b4.z, b4.w};
        u32 hw[4], lw[4];
#pragma unroll
        for (int e = 0; e < 4; e++) {
            u16 h0, l0, h1, l1;
            split2(xs[2 * e], h0, l0);
            split2(xs[2 * e + 1], h1, l1);
            hw[e] = (u32)h0 | ((u32)h1 << 16);
            lw[e] = (u32)l0 | ((u32)l1 << 16);
        }
        *(uint4*)(dt + region * 512 + lane * 8)        = make_uint4(hw[0], hw[1], hw[2], hw[3]);
        *(uint4*)(dt + 2048 + region * 512 + lane * 8) = make_uint4(lw[0], lw[1], lw[2], lw[3]);
        return;
    }
    const int r = tid >> 3, f = tid & 7;
    const float* p = src + soff + (size_t)r * 512 + (size_t)f * 8;
    float4 a  = *(const float4*)p;
    float4 b4 = *(const float4*)(p + 4);
    if (mode == 2) {
        *(float4*)&tf[r][f * 8]     = a;
        *(float4*)&tf[r][f * 8 + 4] = b4;
        __syncthreads();
        const int ntd = tid >> 6, lane = tid & 63;
        const int q2 = lane >> 4, c2 = lane & 15;
        u32 hw[4], lw[4];
#pragma unroll
        for (int e = 0; e < 4; e++) {
            u16 h0, l0, h1, l1;
            split2(tf[q2 * 8 + 2 * e][ntd * 16 + c2], h0, l0);
            split2(tf[q2 * 8 + 2 * e + 1][ntd * 16 + c2], h1, l1);
            hw[e] = (u32)h0 | ((u32)h1 << 16);
            lw[e] = (u32)l0 | ((u32)l1 << 16);
        }
        *(uint4*)(dt + ntd * 512 + lane * 8)        = make_uint4(hw[0], hw[1], hw[2], hw[3]);
        *(uint4*)(dt + 2048 + ntd * 512 + lane * 8) = make_uint4(lw[0], lw[1], lw[2], lw[3]);
    } else {
        float xs[8] = {a.x, a.y, a.z, a.w, b4.x, b4.y, b4.z, b4.w};
        u32 hw[4], lw[4];
#pragma unroll
        for (int e = 0; e < 4; e++) {
            u16 h0, l0, h1, l1;
            split2(xs[2 * e], h0, l0);
            split2(xs[2 * e + 1], h1, l1);
            hw[e] = (u32)h0 | ((u32)h1 << 16);
            lw[e] = (u32)l0 | ((u32)l1 << 16);
        }
        const int s = f >> 2, kq = f & 3, nt = r >> 4, n = r & 15;
        const int g = nt * 128 + n * 8 + ((4 * s + kq + 5 * n) & 7);
        *(uint4*)(dt + g * 8)        = make_uint4(hw[0], hw[1], hw[2], hw[3]);
        *(uint4*)(dt + 2048 + g * 8) = make_uint4(lw[0], lw[1], lw[2], lw[3]);
    }
}

// ---------------------------------------------------------------------------
// Prepack a GEMM A-operand: fp32 [4096,512] -> 32-row x 64-k hi/lo granule
// tiles (swizzled, mode-0 layout). Grid 1024.
// ---------------------------------------------------------------------------
__global__ __launch_bounds__(256) void prepack_a_kernel(
    const float* __restrict__ src, u16* __restrict__ dst) {
    const int bid = blockIdx.x, tid = threadIdx.x;
    const int r = tid >> 3, f = tid & 7;
    const float* p = src + ((size_t)(bid >> 3) * 32 + r) * 512
                         + (size_t)(bid & 7) * 64 + f * 8;
    float4 a  = *(const float4*)p;
    float4 b4 = *(const float4*)(p + 4);
    float xs[8] = {a.x, a.y, a.z, a.w, b4.x, b4.y, b4.z, b4.w};
    u32 hw[4], lw[4];
#pragma unroll
    for (int e = 0; e < 4; e++) {
        u16 h0, l0, h1, l1;
        split2(xs[2 * e], h0, l0);
        split2(xs[2 * e + 1], h1, l1);
        hw[e] = (u32)h0 | ((u32)h1 << 16);
        lw[e] = (u32)l0 | ((u32)l1 << 16);
    }
    const int s = f >> 2, kq = f & 3, nt = r >> 4, n = r & 15;
    const int g = nt * 128 + n * 8 + ((4 * s + kq + 5 * n) & 7);
    u16* dt = dst + (size_t)bid * 4096;
    *(uint4*)(dt + g * 8)        = make_uint4(hw[0], hw[1], hw[2], hw[3]);
    *(uint4*)(dt + 2048 + g * 8) = make_uint4(lw[0], lw[1], lw[2], lw[3]);
}

// ---------------------------------------------------------------------------
// Prepack 5 weight matrices [512,512] into B-frag hi/lo granule tiles of
// 32 cols x 64 k (transposed via LDS). Grid 640.
// ---------------------------------------------------------------------------
__global__ __launch_bounds__(256) void prepack_w_kernel(
    const float* __restrict__ W0, const float* __restrict__ W1,
    const float* __restrict__ W2, const float* __restrict__ W3,
    const float* __restrict__ W4, u16* __restrict__ dst) {
    __shared__ float tw[64][36];
    const int bid = blockIdx.x, tid = threadIdx.x;
    const int widx = bid >> 7, loc = bid & 127;
    const int nb2 = loc >> 3, kb = loc & 7;
    const float* Wsrc = widx == 0 ? W0 : widx == 1 ? W1 : widx == 2 ? W2
                      : widx == 3 ? W3 : W4;
    const int kl = tid >> 2, gr = tid & 3;
    const float* p = Wsrc + (size_t)(kb * 64 + kl) * 512 + nb2 * 32 + gr * 8;
    float4 a  = *(const float4*)p;
    float4 b4 = *(const float4*)(p + 4);
    *(float4*)&tw[kl][gr * 8]     = a;
    *(float4*)&tw[kl][gr * 8 + 4] = b4;
    __syncthreads();
    const int n5 = tid >> 3, f = tid & 7, s = f >> 2, kq = f & 3;
    u32 hw[4], lw[4];
#pragma unroll
    for (int e = 0; e < 4; e++) {
        u16 h0, l0, h1, l1;
        split2(tw[s * 32 + kq * 8 + 2 * e][n5], h0, l0);
        split2(tw[s * 32 + kq * 8 + 2 * e + 1][n5], h1, l1);
        hw[e] = (u32)h0 | ((u32)h1 << 16);
        lw[e] = (u32)l0 | ((u32)l1 << 16);
    }
    const int n = n5 & 15, nt = n5 >> 4;
    const int g = nt * 128 + n * 8 + ((4 * s + kq + 5 * n) & 7);
    u16* dt = dst + (size_t)bid * 4096;
    *(uint4*)(dt + g * 8)        = make_uint4(hw[0], hw[1], hw[2], hw[3]);
    *(uint4*)(dt + 2048 + g * 8) = make_uint4(lw[0], lw[1], lw[2], lw[3]);
}

// ---------------------------------------------------------------------------
// MFMA GEMM, bf16 hi/lo emulation (unchanged from R6 — validated).
// ---------------------------------------------------------------------------
__global__ __launch_bounds__(256, 2) void gemm_mfma_kernel(
    const u16* __restrict__ Apk, const u16* __restrict__ Wpk,
    const float* __restrict__ bias, float* __restrict__ C) {
    __shared__ __align__(16) u16 Stage[2][16384];

    const int tid = threadIdx.x;
    const int w = tid >> 6, lane = tid & 63, quad = lane >> 4, c = lane & 15;
    const int bx = blockIdx.x;
    const int mp = bx & 63, nb = bx >> 6;
    const int mq = w >> 1, nq = w & 1;

    auto stage_async = [&](int kb, int half) {
        const u16* s = (w < 2)
            ? Apk + (size_t)((2 * mp + w) * 8 + kb) * 4096
            : Wpk + (size_t)((2 * nb + (w & 1)) * 8 + kb) * 4096;
        const u16* g = s + lane * 8;
        u16* d = Stage[half] + w * 4096;
#pragma unroll
        for (int u2 = 0; u2 < 8; u2++)
            load_lds16(g + u2 * 512, d + u2 * 512);
    };

    stage_async(0, 0);

    f32x4 acc[2][2];
#pragma unroll
    for (int mh = 0; mh < 2; mh++)
#pragma unroll
        for (int nh = 0; nh < 2; nh++) acc[mh][nh] = (f32x4){0.f, 0.f, 0.f, 0.f};

    for (int kb = 0; kb < 8; kb++) {
        const int half = kb & 1;
        __syncthreads();
        if (kb < 7) stage_async(kb + 1, 1 - half);
        const u16* Ab = Stage[half] + mq * 4096;
        const u16* Wb = Stage[half] + 8192 + nq * 4096;
#pragma unroll
        for (int s = 0; s < 2; s++) {
            bf16x8 ah[2], al[2], wh[2], wl[2];
#pragma unroll
            for (int t = 0; t < 2; t++) {
                int g = (t << 7) + (c << 3) + (((s << 2) + quad + 5 * c) & 7);
                ah[t] = *(const bf16x8*)(Ab + g * 8);
                al[t] = *(const bf16x8*)(Ab + 2048 + g * 8);
                wh[t] = *(const bf16x8*)(Wb + g * 8);
                wl[t] = *(const bf16x8*)(Wb + 2048 + g * 8);
            }
#pragma unroll
            for (int mh = 0; mh < 2; mh++)
#pragma unroll
                for (int nh = 0; nh < 2; nh++) {
                    acc[mh][nh] = __builtin_amdgcn_mfma_f32_16x16x32_bf16(
                        ah[mh], wh[nh], acc[mh][nh], 0, 0, 0);
                    acc[mh][nh] = __builtin_amdgcn_mfma_f32_16x16x32_bf16(
                        ah[mh], wl[nh], acc[mh][nh], 0, 0, 0);
                    acc[mh][nh] = __builtin_amdgcn_mfma_f32_16x16x32_bf16(
                        al[mh], wh[nh], acc[mh][nh], 0, 0, 0);
                }
        }
    }

    const int m0 = mp * 64 + mq * 32, n0 = nb * 64 + nq * 32;
    float bv0 = bias ? bias[n0 + c] : 0.f;
    float bv1 = bias ? bias[n0 + 16 + c] : 0.f;
#pragma unroll
    for (int mh = 0; mh < 2; mh++)
#pragma unroll
        for (int r = 0; r < 4; r++) {
            size_t row = (size_t)(m0 + mh * 16 + quad * 4 + r) * 512;
            C[row + n0 + c]      = acc[mh][0][r] + bv0;
            C[row + n0 + 16 + c] = acc[mh][1][r] + bv1;
        }
}

// ---------------------------------------------------------------------------
// MFMA flash attention, split-j (2 halves of 1024 cols) with final merge.
// Block = (b, h, 64 Q rows, j-half), 4 waves, wave w owns rows 16w..16w+15.
// h in LOW blockIdx bits -> XCD L2 locality.
//
// K: LDS DMA double-buffer (2x8KB, shared across waves, 1 barrier/jt).
// V, R: read DIRECTLY from global in lane-order coalesced frag layout
//   (1 frag = one coalesced 1KB load; per-XCD set ~3MB, L2-resident).
// rel2 ring: per-wave LDS, 3 slots x 16 x 35 (live window = 3 chunks),
//   rotating uniform slot bases rb0/rb1/rb2; gather offset
//   off = 64-16w+16nt+c-4q-r is jt-INDEPENDENT (d = off>>5 picks slot).
// Epilogue: unnormalized O + (m,l) per row -> merge kernel combines halves.
// ---------------------------------------------------------------------------
__global__ __launch_bounds__(256, 3) void attn_mfma_kernel(
    const float* __restrict__ q, const u16* __restrict__ Kpk,
    const u16* __restrict__ Vpk, const u16* __restrict__ Rpk,
    const float* __restrict__ cbk, const float* __restrict__ rbrk,
    float* __restrict__ Op0, float* __restrict__ Op1,
    float2* __restrict__ mlbuf) {
    __shared__ __align__(16) u16 Stage[2][4096];   // K double-buffer (16 KB)
    __shared__ float Ring[4][3 * 560];             // per-wave 3 slots x 16x35
    __shared__ u32 Pbuf[4 * 544];                  // [wave][16][34]

    const int tid = threadIdx.x;
    const int w = tid >> 6, lane = tid & 63, quad = lane >> 4, c = lane & 15;
    const int bx = blockIdx.x;
    const int h = bx & 7, b = (bx >> 3) & 1, jh = (bx >> 4) & 1, it0 = bx >> 5;
    const int i0 = it0 * 64;
    const size_t bh_off = (size_t)b * TT * DD + (size_t)h * DK;

    // ---- Q A-frags (hi/lo), prescaled 1/8; row = i0+16w+c, k = 32s+8quad+j
    frag_u qh[2], ql[2];
    {
        const float* qrow = q + bh_off + (size_t)(i0 + 16 * w + c) * DD;
#pragma unroll
        for (int s = 0; s < 2; s++) {
            int d0 = s * 32 + quad * 8;
            float4 a  = *(const float4*)(qrow + d0);
            float4 b4 = *(const float4*)(qrow + d0 + 4);
            float xs[8] = {a.x, a.y, a.z, a.w, b4.x, b4.y, b4.z, b4.w};
#pragma unroll
            for (int j2 = 0; j2 < 8; j2++)
                split2(xs[j2] * 0.125f, qh[s].u[j2], ql[s].u[j2]);
        }
    }

    const u16* Ktiles  = Kpk + (size_t)(b * HH + h) * 64 * 4096;
    const u16* Vtiles  = Vpk + (size_t)(b * HH + h) * 64 * 4096;
    const u16* Rchunks = Rpk + (size_t)h * 128 * 4096;
    const float* rbrk_h = rbrk + (size_t)h * (2 * TT);
    const float* cbk_h  = cbk + ((size_t)h * BB + b) * TT;

    auto read_kr = [&](const u16* reg, int nt, int s, bf16x8& fh, bf16x8& fl) {
        int g = (nt << 7) + (c << 3) + (((s << 2) + quad + 5 * c) & 7);
        fh = *(const bf16x8*)(reg + g * 8);
        fl = *(const bf16x8*)(reg + 2048 + g * 8);
    };

    const int k0c = (TT - i0 - 63 + 1024 * jh) >> 5;   // window start chunk

    int rb0 = 0, rb1 = 560, rb2 = 1120;   // rotating slot bases (floats)

    // produce rel2 chunk cidx into this wave's ring at slot base `base`.
    // R frags: coalesced 1KB global loads (L2-hot). rbrk folded in.
    auto produce = [&](int cidx, int base) {
        const u16* Rc = Rchunks + (size_t)cidx * 4096;
        float* ringw = Ring[w] + base;
#pragma unroll
        for (int ntp = 0; ntp < 2; ntp++) {
            f32x4 acc = {0.f, 0.f, 0.f, 0.f};
#pragma unroll
            for (int s = 0; s < 2; s++) {
                bf16x8 fh = *(const bf16x8*)(Rc + ((ntp * 2 + s) << 9) + lane * 8);
                bf16x8 fl = *(const bf16x8*)(Rc + 2048 + ((ntp * 2 + s) << 9) + lane * 8);
                acc = __builtin_amdgcn_mfma_f32_16x16x32_bf16(qh[s].f, fh, acc, 0, 0, 0);
                acc = __builtin_amdgcn_mfma_f32_16x16x32_bf16(qh[s].f, fl, acc, 0, 0, 0);
                acc = __builtin_amdgcn_mfma_f32_16x16x32_bf16(ql[s].f, fh, acc, 0, 0, 0);
            }
            float rbv = rbrk_h[cidx * 32 + ntp * 16 + c];
            int mpos = ntp * 16 + c;
#pragma unroll
            for (int r = 0; r < 4; r++)
                ringw[(quad * 4 + r) * 35 + mpos] = acc[r] + rbv;
        }
    };

    // DMA K tile (8 chunks of 1KB; wave w issues 2) into Stage[half].
    auto stage_async = [&](int jn, int half) {
        const u16* Ks = Ktiles + (size_t)(jh * 32 + jn) * 4096;
#pragma unroll
        for (int u = 0; u < 2; u++) {
            int of = (w * 2 + u) << 9;
            load_lds16(Ks + of + lane * 8, Stage[half] + of);
        }
    };

    stage_async(0, 0);
    produce(k0c, rb0);
    produce(k0c + 1, rb1);

    float m_run[4], l_run[4];
    f32x4 o[4];
#pragma unroll
    for (int r = 0; r < 4; r++) { m_run[r] = -INFINITY; l_run[r] = 0.f; }
#pragma unroll
    for (int nt = 0; nt < 4; nt++) o[nt] = (f32x4){0.f, 0.f, 0.f, 0.f};

    for (int jt = 0; jt < 32; jt++) {
        const int j0 = jh * 1024 + jt * 32;
        const int half = jt & 1;
        const u16* Kb = Stage[half];
        __syncthreads();   // drains DMA (vmcnt0 at barrier), orders buffer reuse
        if (jt < 31) stage_async(jt + 1, 1 - half);

        produce(k0c + jt + 2, rb2);   // per-wave; same-wave reads below

        // ---- S = QK (MFMA, K from LDS) + ring rel gather + cbk ----
        float sv[2][4];
#pragma unroll
        for (int nt = 0; nt < 2; nt++) {
            f32x4 sc = {0.f, 0.f, 0.f, 0.f};
#pragma unroll
            for (int s = 0; s < 2; s++) {
                bf16x8 fh, fl;
                read_kr(Kb, nt, s, fh, fl);
                sc = __builtin_amdgcn_mfma_f32_16x16x32_bf16(qh[s].f, fh, sc, 0, 0, 0);
                sc = __builtin_amdgcn_mfma_f32_16x16x32_bf16(qh[s].f, fl, sc, 0, 0, 0);
                sc = __builtin_amdgcn_mfma_f32_16x16x32_bf16(ql[s].f, fh, sc, 0, 0, 0);
            }
            float cbv = cbk_h[j0 + nt * 16 + c];
#pragma unroll
            for (int r = 0; r < 4; r++) {
                // off in [1,95], jt-independent; d = off>>5 picks live slot
                int off = 64 - 16 * w + nt * 16 + c - quad * 4 - r;
                int d = off >> 5;
                int bse = (d == 0) ? rb0 : ((d == 1) ? rb1 : rb2);
                float rel = Ring[w][bse + (quad * 4 + r) * 35 + (off & 31)];
                sv[nt][r] = sc[r] + rel + cbv;
            }
        }

        // ---- online softmax (16 lanes per row) + P write (packed u32) ----
#pragma unroll
        for (int r = 0; r < 4; r++) {
            float tm = fmaxf(sv[0][r], sv[1][r]);
#pragma unroll
            for (int off = 1; off < 16; off <<= 1) tm = fmaxf(tm, __shfl_xor(tm, off));
            float mnew = fmaxf(m_run[r], tm);
            float al = __expf(m_run[r] - mnew);
            float p0 = __expf(sv[0][r] - mnew);
            float p1 = __expf(sv[1][r] - mnew);
            float ps = p0 + p1;
#pragma unroll
            for (int off = 1; off < 16; off <<= 1) ps += __shfl_xor(ps, off);
            l_run[r] = l_run[r] * al + ps;
            m_run[r] = mnew;
#pragma unroll
            for (int nt = 0; nt < 4; nt++) o[nt][r] *= al;
            u32* pb = Pbuf + w * 544 + (quad * 4 + r) * 34;
            pb[c]      = split_pack(p0);
            pb[16 + c] = split_pack(p1);
        }

        // ---- O += P @ V (hi/lo); V frags = coalesced global loads ----
        frag_u ph, pl;
        {
            const u32* pb = Pbuf + w * 544 + c * 34 + quad * 8;
            uint2 r0 = *(const uint2*)(pb);
            uint2 r1 = *(const uint2*)(pb + 2);
            uint2 r2 = *(const uint2*)(pb + 4);
            uint2 r3 = *(const uint2*)(pb + 6);
            u32 pk[8] = {r0.x, r0.y, r1.x, r1.y, r2.x, r2.y, r3.x, r3.y};
#pragma unroll
            for (int j2 = 0; j2 < 8; j2++) {
                ph.u[j2] = (u16)(pk[j2] >> 16);
                pl.u[j2] = (u16)(pk[j2] & 0xffffu);
            }
        }
        const u16* Vt = Vtiles + (size_t)(jh * 32 + jt) * 4096;
#pragma unroll
        for (int ntd = 0; ntd < 4; ntd++) {
            bf16x8 vh = *(const bf16x8*)(Vt + (ntd << 9) + lane * 8);
            bf16x8 vl = *(const bf16x8*)(Vt + 2048 + (ntd << 9) + lane * 8);
            o[ntd] = __builtin_amdgcn_mfma_f32_16x16x32_bf16(ph.f, vh, o[ntd], 0, 0, 0);
            o[ntd] = __builtin_amdgcn_mfma_f32_16x16x32_bf16(ph.f, vl, o[ntd], 0, 0, 0);
            o[ntd] = __builtin_amdgcn_mfma_f32_16x16x32_bf16(pl.f, vh, o[ntd], 0, 0, 0);
        }

        // rotate ring slot bases
        int t0 = rb0; rb0 = rb1; rb1 = rb2; rb2 = t0;
    }

    // ---- epilogue: UNNORMALIZED O + (m,l) per row ----
    float* Op = jh ? Op1 : Op0;
#pragma unroll
    for (int nt = 0; nt < 4; nt++) {
#pragma unroll
        for (int r = 0; r < 4; r++) {
            int i_abs = i0 + 16 * w + quad * 4 + r;
            Op[((size_t)b * TT + i_abs) * DD + h * DK + nt * 16 + c] = o[nt][r];
        }
    }
    if (c == 0) {
#pragma unroll
        for (int r = 0; r < 4; r++) {
            int i_abs = i0 + 16 * w + quad * 4 + r;
            mlbuf[(size_t)jh * (BB * HH * TT) + ((size_t)b * HH + h) * TT + i_abs]
                = make_float2(m_run[r], l_run[r]);
        }
    }
}

// ---------------------------------------------------------------------------
// Merge the two j-halves: out = (w1*O0 + w2*O1) / (w1*l1 + w2*l2), in-place
// into O0 (same element index -> no aliasing hazard).
// ---------------------------------------------------------------------------
__global__ __launch_bounds__(256) void merge_kernel(
    float* __restrict__ O0, const float* __restrict__ O1,
    const float2* __restrict__ mlbuf) {
    int x = blockIdx.x * 256 + threadIdx.x;        // 2M elements
    int b = x >> 20;                                // TT*DD = 2^20
    int i = (x >> 9) & (TT - 1);
    int h = (x >> 6) & 7;
    int row = (b * HH + h) * TT + i;
    float2 a = mlbuf[row];
    float2 c2 = mlbuf[BB * HH * TT + row];
    float m = fmaxf(a.x, c2.x);
    float w1 = __expf(a.x - m), w2 = __expf(c2.x - m);
    float inv = 1.0f / (w1 * a.y + w2 * c2.y);
    O0[x] = (w1 * O0[x] + w2 * O1[x]) * inv;
}

// ---------------------------------------------------------------------------
extern "C" void kernel_launch(void* const* d_in, const int* in_sizes, int n_in,
                              void* d_out, int out_size, void* d_ws, size_t ws_size,
                              hipStream_t stream) {
    const float* query  = (const float*)d_in[0];
    const float* key_in = (const float*)d_in[1];
    const float* value  = (const float*)d_in[2];
    const float* Wq = (const float*)d_in[3];
    const float* bq = (const float*)d_in[4];
    const float* Wk = (const float*)d_in[5];
    const float* bk = (const float*)d_in[6];
    const float* Wv = (const float*)d_in[7];
    const float* bv = (const float*)d_in[8];
    const float* Wr = (const float*)d_in[9];
    const float* cb = (const float*)d_in[10];
    const float* rb = (const float*)d_in[11];
    const float* Wo = (const float*)d_in[12];
    const float* bo = (const float*)d_in[13];
    float* out = (float*)d_out;

    float* ws = (float*)d_ws;
    const size_t SL = (size_t)MM * DD;        // 2097152 floats (8 MB) per slot
    float* qb    = ws;                        // fp32 Q [B,T,H,Dk]
    float* kb    = ws + SL;                   // fp32 K (consumed, then Rpk)
    float* vb    = ws + 2 * SL;               // fp32 V (consumed, then Kpk)
    float* relk  = ws + 3 * SL;               // fp32 relK [2T,H,Dk]
    float* attnv = ws + 4 * SL;               // pe first, then Op0/merged attn
    float* pe    = attnv;
    float* Op0   = attnv;                     // attn partial half 0 (-> merged)
    u16*   Vpk   = (u16*)(ws + 5 * SL);       // packed V tiles (8 MB)
    u16*   Kpk   = (u16*)vb;                  // packed K tiles (8 MB)
    u16*   Rpk   = (u16*)kb;                  // packed R chunks (8 MB)
    u16*   Apk   = (u16*)(ws + 6 * SL);       // packed GEMM A operand
    float* Op1   = ws + 6 * SL;               // attn partial half 1 (shares Apk)
    u16*   Wpk   = (u16*)(ws + 7 * SL);       // packed weights, 5 x 1 MB
    float* cbk   = ws + 7 * SL + 1310720;     // [H*B*T]
    float* rbrk  = cbk + BB * TT * HH;        // [H*2T]
    float2* mlbuf = (float2*)(rbrk + 2 * TT * HH);  // 2 x 32768 float2
    const size_t WSZ = 128 * 4096;            // u16 per packed weight

    prepack_w_kernel<<<640, 256, 0, stream>>>(Wq, Wk, Wv, Wr, Wo, Wpk);
    pe_kernel<<<(2 * TT * DD) / 256, 256, 0, stream>>>(pe);

    prepack_a_kernel<<<1024, 256, 0, stream>>>(pe, Apk);
    gemm_mfma_kernel<<<512, 256, 0, stream>>>(Apk, Wpk + 3 * WSZ, nullptr, relk);
    prepack_a_kernel<<<1024, 256, 0, stream>>>(query, Apk);
    gemm_mfma_kernel<<<512, 256, 0, stream>>>(Apk, Wpk + 0 * WSZ, bq, qb);
    prepack_a_kernel<<<1024, 256, 0, stream>>>(key_in, Apk);
    gemm_mfma_kernel<<<512, 256, 0, stream>>>(Apk, Wpk + 1 * WSZ, bk, kb);
    prepack_a_kernel<<<1024, 256, 0, stream>>>(value, Apk);
    gemm_mfma_kernel<<<512, 256, 0, stream>>>(Apk, Wpk + 2 * WSZ, bv, vb);

    bias_dots_kernel<<<(BB * TT * HH + 2 * TT * HH) / 256, 256, 0, stream>>>(
        kb, relk, cb, rb, cbk, rbrk);
    // prepack order matters (aliasing): V first (frees vb), then K (-> vb),
    // then R (-> kb, after K consumed kb).
    prepack_kernel<<<1024, 256, 0, stream>>>(vb, Vpk, 2);
    prepack_kernel<<<1024, 256, 0, stream>>>(kb, Kpk, 0);
    prepack_kernel<<<1024, 256, 0, stream>>>(relk, Rpk, 1);
    // split-j flash attention (grid 1024 = 2x8x2x32, h in low bits)
    attn_mfma_kernel<<<BB * HH * 2 * (TT / 64), 256, 0, stream>>>(
        qb, Kpk, Vpk, Rpk, cbk, rbrk, Op0, Op1, mlbuf);
    merge_kernel<<<(MM * DD) / 256, 256, 0, stream>>>(Op0, Op1, mlbuf);
    // output projection (Apk overwrites Op1 only after merge consumed it)
    prepack_a_kernel<<<1024, 256, 0, stream>>>(attnv, Apk);
    gemm_mfma_kernel<<<512, 256, 0, stream>>>(Apk, Wpk + 4 * WSZ, bo, out);
}